// Round 3
// baseline (334.995 us; speedup 1.0000x reference)
//
#include <hip/hip_runtime.h>
#include <math.h>

#define POUT 7
#define NCH 256

// ---------------- level geometry (elements) ----------------
#define HW0 40000
#define HW1 10000
#define HW2 2500
#define HW3 625
#define WS_OFF0 0
#define WS_OFF1 (2*NCH*HW0)
#define WS_OFF2 (WS_OFF1 + 2*NCH*HW1)
#define WS_OFF3 (WS_OFF2 + 2*NCH*HW2)
#define WS_ELEMS (WS_OFF3 + 2*NCH*HW3)      // 27,200,000 floats = 108.8 MB

#define MAXSPAN 208                          // >= max map dim (200) + pad

// ---------------- NCHW -> NHWC tiled transpose ----------------
__global__ __launch_bounds__(256) void transpose_cl_kernel(
    const float* __restrict__ in, float* __restrict__ out, int HW)
{
    __shared__ float tile[32][33];
    const int p0 = blockIdx.x * 32;
    const int c0 = blockIdx.y * 32;
    const int b  = blockIdx.z;
    const int tx = threadIdx.x, ty = threadIdx.y;

    const float* src = in + ((size_t)b * NCH + c0) * (size_t)HW + p0;
    #pragma unroll
    for (int j = 0; j < 32; j += 8) {
        const int c = ty + j;
        if (p0 + tx < HW) tile[c][tx] = src[(size_t)c * HW + tx];
    }
    __syncthreads();
    float* dst = out + ((size_t)b * HW + p0) * NCH + c0;
    #pragma unroll
    for (int j = 0; j < 32; j += 8) {
        const int p = ty + j;
        if (p0 + p < HW) dst[(size_t)p * NCH + tx] = tile[tx][p];
    }
}

// ---------------- separable RoIAlign from NHWC ----------------
// One block per box, thread t = channel c. out[p,q] = Wy . F . Wx^T per
// channel: region read once (coalesced 256B loads), 7 FMA/elem, weights
// broadcast from LDS. Output staged through LDS for coalesced float4 stores.
__global__ __launch_bounds__(256, 4) void roi_sep_kernel(
    const float* __restrict__ ws, const float* __restrict__ props,
    float* __restrict__ out, int boxes_per_img)
{
    __shared__ float  sWy[MAXSPAN][8];     // [y][p], p<7 used
    __shared__ float  sWx[MAXSPAN][8];     // [x][q], q<7 used (0.25 folded in)
    __shared__ float4 sStage4[64 * 49 / 4]; // per-wave 64ch x 49bin staging

    const int n = blockIdx.x;
    const int t = threadIdx.x;
    const int b = n / boxes_per_img;

    const float4 box = ((const float4*)props)[n];
    const float area = (box.z - box.x) * (box.w - box.y);
    float lvlf = floorf(4.0f + log2f(sqrtf(area) / 224.0f + 1e-6f));
    lvlf = fminf(fmaxf(lvlf, 2.0f), 5.0f) - 2.0f;
    const int l = (int)lvlf;

    int sz; size_t lvl_off;
    if      (l == 0) { sz = 200; lvl_off = WS_OFF0; }
    else if (l == 1) { sz = 100; lvl_off = WS_OFF1; }
    else if (l == 2) { sz = 50;  lvl_off = WS_OFF2; }
    else             { sz = 25;  lvl_off = WS_OFF3; }
    const int HW = sz * sz;
    const float scale = 0.25f / (float)(1 << l);

    const float x0s = box.x * scale, y0s = box.y * scale;
    const float x1s = box.z * scale, y1s = box.w * scale;
    const float bin_w = fmaxf(x1s - x0s, 1.0f) / (float)POUT;
    const float bin_h = fmaxf(y1s - y0s, 1.0f) / (float)POUT;

    // region bounds (sample coords are monotone in sample index):
    // first sample j=0 -> +0.25*bin, last j=13 -> +6.75*bin
    auto lo_of = [sz](float coord) -> int {
        float cc = fmaxf(coord, 0.0f);
        int lo0 = (int)floorf(cc);
        return (lo0 >= sz - 1) ? sz - 1 : lo0;
    };
    auto hi_of = [sz](float coord) -> int {
        float cc = fmaxf(coord, 0.0f);
        int lo0 = (int)floorf(cc);
        return (lo0 >= sz - 1) ? sz - 1 : lo0 + 1;
    };
    const int ymin = lo_of(y0s + 0.25f * bin_h);
    const int ymax = hi_of(y0s + 6.75f * bin_h);
    const int xmin = lo_of(x0s + 0.25f * bin_w);
    const int xmax = hi_of(x0s + 6.75f * bin_w);
    const int R  = ymax - ymin + 1;          // <= sz <= 200
    const int Cl = xmax - xmin + 1;

    // zero the used weight rows
    for (int i = t; i < R * 8; i += 256)  ((float*)sWy)[i] = 0.0f;
    for (int i = t; i < Cl * 8; i += 256) ((float*)sWx)[i] = 0.0f;
    __syncthreads();

    // build weights: threads 0..6 own Wy row p; threads 64..70 own Wx col q
    if (t < 7) {
        #pragma unroll
        for (int iy = 0; iy < 2; ++iy) {
            const float yc = y0s + ((float)t + ((float)iy + 0.5f) * 0.5f) * bin_h;
            const bool  v  = (yc >= -1.0f) && (yc <= (float)sz);
            const float cc = fmaxf(yc, 0.0f);
            const int lo0  = (int)floorf(cc);
            const bool edge = lo0 >= sz - 1;
            const int lo = edge ? sz - 1 : lo0;
            const int hi = edge ? sz - 1 : lo0 + 1;
            const float fr = edge ? 0.0f : cc - (float)lo0;
            const float m  = v ? 1.0f : 0.0f;
            sWy[lo - ymin][t] += (1.0f - fr) * m;
            sWy[hi - ymin][t] += fr * m;
        }
    } else if (t >= 64 && t < 71) {
        const int q = t - 64;
        #pragma unroll
        for (int ix = 0; ix < 2; ++ix) {
            const float xc = x0s + ((float)q + ((float)ix + 0.5f) * 0.5f) * bin_w;
            const bool  v  = (xc >= -1.0f) && (xc <= (float)sz);
            const float cc = fmaxf(xc, 0.0f);
            const int lo0  = (int)floorf(cc);
            const bool edge = lo0 >= sz - 1;
            const int lo = edge ? sz - 1 : lo0;
            const int hi = edge ? sz - 1 : lo0 + 1;
            const float fr = edge ? 0.0f : cc - (float)lo0;
            const float m  = v ? 0.25f : 0.0f;   // fold subsample mean
            sWx[lo - xmin][q] += (1.0f - fr) * m;
            sWx[hi - xmin][q] += fr * m;
        }
    }
    __syncthreads();

    // main separable accumulation, lane = channel
    const float* fb = ws + lvl_off + (size_t)b * (size_t)HW * NCH + t;
    const int ystride = sz * NCH;

    float acc[49];
    #pragma unroll
    for (int i = 0; i < 49; ++i) acc[i] = 0.0f;

    for (int xi = 0; xi < Cl; ++xi) {
        float wq[8];
        *(float4*)&wq[0] = *(const float4*)&sWx[xi][0];
        *(float4*)&wq[4] = *(const float4*)&sWx[xi][4];

        float col[7];
        #pragma unroll
        for (int p = 0; p < 7; ++p) col[p] = 0.0f;

        const float* py = fb + ((size_t)ymin * sz + (xmin + xi)) * NCH;
        int y = 0;
        for (; y + 4 <= R; y += 4) {
            const float v0 = py[0];
            const float v1 = py[ystride];
            const float v2 = py[2 * (size_t)ystride];
            const float v3 = py[3 * (size_t)ystride];
            float w0[8], w1[8], w2[8], w3[8];
            *(float4*)&w0[0] = *(const float4*)&sWy[y + 0][0];
            *(float4*)&w0[4] = *(const float4*)&sWy[y + 0][4];
            *(float4*)&w1[0] = *(const float4*)&sWy[y + 1][0];
            *(float4*)&w1[4] = *(const float4*)&sWy[y + 1][4];
            *(float4*)&w2[0] = *(const float4*)&sWy[y + 2][0];
            *(float4*)&w2[4] = *(const float4*)&sWy[y + 2][4];
            *(float4*)&w3[0] = *(const float4*)&sWy[y + 3][0];
            *(float4*)&w3[4] = *(const float4*)&sWy[y + 3][4];
            #pragma unroll
            for (int p = 0; p < 7; ++p)
                col[p] += w0[p] * v0 + w1[p] * v1 + w2[p] * v2 + w3[p] * v3;
            py += 4 * (size_t)ystride;
        }
        for (; y < R; ++y) {
            const float v = py[0];
            float w[8];
            *(float4*)&w[0] = *(const float4*)&sWy[y][0];
            *(float4*)&w[4] = *(const float4*)&sWy[y][4];
            #pragma unroll
            for (int p = 0; p < 7; ++p) col[p] += w[p] * v;
            py += (size_t)ystride;
        }

        #pragma unroll
        for (int p = 0; p < 7; ++p)
            #pragma unroll
            for (int q = 0; q < 7; ++q)
                acc[p * 7 + q] += col[p] * wq[q];
    }

    // staged coalesced output: out[n][c][p][q], 12544 floats per box
    float* sStage = (float*)sStage4;
    const int wave = t >> 6, lane = t & 63;
    float* obase = out + (size_t)n * (NCH * 49);
    for (int w = 0; w < 4; ++w) {
        if (wave == w) {
            #pragma unroll
            for (int i = 0; i < 49; ++i) sStage[lane * 49 + i] = acc[i];
        }
        __syncthreads();
        float4* op4 = (float4*)(obase + w * 64 * 49);
        for (int i = t; i < 64 * 49 / 4; i += 256) op4[i] = sStage4[i];
        __syncthreads();
    }
}

// ---------------- fallback (round-1 NCHW kernel) ----------------
__global__ __launch_bounds__(256, 4) void roi_align_nchw_kernel(
    const float* __restrict__ f0, const float* __restrict__ f1,
    const float* __restrict__ f2, const float* __restrict__ f3,
    const float* __restrict__ props, float* __restrict__ out, int boxes_per_img)
{
    const int n = blockIdx.x;
    const int t = threadIdx.x;
    if (t >= 196) return;
    const int bin = t >> 2, q = t & 3;
    const int ph = bin / POUT, pw = bin % POUT;
    const int iy = q >> 1,    ix = q & 1;
    const int b = n / boxes_per_img;

    const float4 box = ((const float4*)props)[n];
    const float area = (box.z - box.x) * (box.w - box.y);
    float lvlf = floorf(4.0f + log2f(sqrtf(area) / 224.0f + 1e-6f));
    lvlf = fminf(fmaxf(lvlf, 2.0f), 5.0f) - 2.0f;
    const int l = (int)lvlf;

    const float* feat; int sz;
    if      (l == 0) { feat = f0; sz = 200; }
    else if (l == 1) { feat = f1; sz = 100; }
    else if (l == 2) { feat = f2; sz = 50;  }
    else             { feat = f3; sz = 25;  }
    const float scale = 0.25f / (float)(1 << l);

    const float x0 = box.x * scale, y0 = box.y * scale;
    const float x1 = box.z * scale, y1 = box.w * scale;
    const float bin_w = fmaxf(x1 - x0, 1.0f) / (float)POUT;
    const float bin_h = fmaxf(y1 - y0, 1.0f) / (float)POUT;
    const float ysamp = y0 + ((float)ph + ((float)iy + 0.5f) * 0.5f) * bin_h;
    const float xsamp = x0 + ((float)pw + ((float)ix + 0.5f) * 0.5f) * bin_w;

    const bool  vy  = (ysamp >= -1.0f) && (ysamp <= (float)sz);
    const float cy  = fmaxf(ysamp, 0.0f);
    const int   yl0 = (int)floorf(cy);
    const bool  ey  = yl0 >= sz - 1;
    const int   yl  = ey ? sz - 1 : yl0;
    const int   yh  = ey ? sz - 1 : yl0 + 1;
    const float ly  = ey ? 0.0f : cy - (float)yl0;
    const bool  vx  = (xsamp >= -1.0f) && (xsamp <= (float)sz);
    const float cx  = fmaxf(xsamp, 0.0f);
    const int   xl0 = (int)floorf(cx);
    const bool  ex  = xl0 >= sz - 1;
    const int   xl  = ex ? sz - 1 : xl0;
    const int   xh  = ex ? sz - 1 : xl0 + 1;
    const float lx  = ex ? 0.0f : cx - (float)xl0;

    const float hy = 1.0f - ly, hx = 1.0f - lx;
    const float m  = (vy && vx) ? 1.0f : 0.0f;
    const float w00 = hy * hx * m, w01 = hy * lx * m;
    const float w10 = ly * hx * m, w11 = ly * lx * m;

    const int HW = sz * sz;
    const float* base = feat + (size_t)b * NCH * HW;
    int o00 = yl * sz + xl, o01 = yl * sz + xh;
    int o10 = yh * sz + xl, o11 = yh * sz + xh;
    float* op = out + (size_t)n * NCH * (POUT * POUT) + bin;

    #pragma unroll 4
    for (int cch = 0; cch < NCH; ++cch) {
        float v = w00 * base[o00] + w01 * base[o01]
                + w10 * base[o10] + w11 * base[o11];
        v += __shfl_xor(v, 1);
        v += __shfl_xor(v, 2);
        if (q == 0) op[cch * (POUT * POUT)] = v * 0.25f;
        o00 += HW; o01 += HW; o10 += HW; o11 += HW;
    }
}

extern "C" void kernel_launch(void* const* d_in, const int* in_sizes, int n_in,
                              void* d_out, int out_size, void* d_ws, size_t ws_size,
                              hipStream_t stream) {
    const float* f0 = (const float*)d_in[0];
    const float* f1 = (const float*)d_in[1];
    const float* f2 = (const float*)d_in[2];
    const float* f3 = (const float*)d_in[3];
    const float* props = (const float*)d_in[4];
    float* out = (float*)d_out;

    const int N = in_sizes[4] / 4;                 // 1024 boxes
    const int B = in_sizes[0] / (NCH * HW0);       // 2 images
    const int boxes_per_img = N / B;               // 512

    if (ws_size >= (size_t)WS_ELEMS * sizeof(float)) {
        float* wsf = (float*)d_ws;
        dim3 blk(32, 8, 1);
        transpose_cl_kernel<<<dim3((HW0 + 31) / 32, 8, B), blk, 0, stream>>>(f0, wsf + WS_OFF0, HW0);
        transpose_cl_kernel<<<dim3((HW1 + 31) / 32, 8, B), blk, 0, stream>>>(f1, wsf + WS_OFF1, HW1);
        transpose_cl_kernel<<<dim3((HW2 + 31) / 32, 8, B), blk, 0, stream>>>(f2, wsf + WS_OFF2, HW2);
        transpose_cl_kernel<<<dim3((HW3 + 31) / 32, 8, B), blk, 0, stream>>>(f3, wsf + WS_OFF3, HW3);
        roi_sep_kernel<<<N, 256, 0, stream>>>(wsf, props, out, boxes_per_img);
    } else {
        roi_align_nchw_kernel<<<N, 256, 0, stream>>>(f0, f1, f2, f3, props, out, boxes_per_img);
    }
}

// Round 4
// 296.029 us; speedup vs baseline: 1.1316x; 1.1316x over previous
//
#include <hip/hip_runtime.h>
#include <math.h>

#define POUT 7
#define NCH 256

// ---------------- level geometry (elements) ----------------
#define HW0 40000
#define HW1 10000
#define HW2 2500
#define HW3 625
#define WS_OFF0 0
#define WS_OFF1 (2*NCH*HW0)
#define WS_OFF2 (WS_OFF1 + 2*NCH*HW1)
#define WS_OFF3 (WS_OFF2 + 2*NCH*HW2)
#define WS_ELEMS (WS_OFF3 + 2*NCH*HW3)      // 27,200,000 floats = 108.8 MB

#define MAXSPAN 208                          // >= max map dim (200) + pad

// ---------------- NCHW -> NHWC tiled transpose ----------------
__global__ __launch_bounds__(256) void transpose_cl_kernel(
    const float* __restrict__ in, float* __restrict__ out, int HW)
{
    __shared__ float tile[32][33];
    const int p0 = blockIdx.x * 32;
    const int c0 = blockIdx.y * 32;
    const int b  = blockIdx.z;
    const int tx = threadIdx.x, ty = threadIdx.y;

    const float* src = in + ((size_t)b * NCH + c0) * (size_t)HW + p0;
    #pragma unroll
    for (int j = 0; j < 32; j += 8) {
        const int c = ty + j;
        if (p0 + tx < HW) tile[c][tx] = src[(size_t)c * HW + tx];
    }
    __syncthreads();
    float* dst = out + ((size_t)b * HW + p0) * NCH + c0;
    #pragma unroll
    for (int j = 0; j < 32; j += 8) {
        const int p = ty + j;
        if (p0 + p < HW) dst[(size_t)p * NCH + tx] = tile[tx][p];
    }
}

// ---------------- separable RoIAlign, latency-optimized ----------------
// Grid = N boxes x 2 channel-halves; block = 128 threads (2 waves), thread t
// owns channel c = half*128 + t. y-outer/x-inner streaming walk, y-unroll 2 +
// x-unroll 4 -> 8 independent loads in flight. Weights in LDS (broadcast
// reads); output staged through the SAME LDS (union) for coalesced stores.
__global__ __launch_bounds__(128, 4) void roi_sep2_kernel(
    const float* __restrict__ ws, const float* __restrict__ props,
    float* __restrict__ out, int boxes_per_img)
{
    // union: weights during accumulation, store-staging afterwards
    __shared__ float smem[MAXSPAN * 16];           // 13312 B
    float* sWy = smem;                             // [MAXSPAN][8]
    float* sWx = smem + MAXSPAN * 8;               // [MAXSPAN][8]

    const int bx   = blockIdx.x;
    const int n    = bx >> 1;
    const int half = bx & 1;
    const int t    = threadIdx.x;                  // 0..127
    const int b    = n / boxes_per_img;

    const float4 box = ((const float4*)props)[n];
    const float area = (box.z - box.x) * (box.w - box.y);
    float lvlf = floorf(4.0f + log2f(sqrtf(area) / 224.0f + 1e-6f));
    lvlf = fminf(fmaxf(lvlf, 2.0f), 5.0f) - 2.0f;
    const int l = (int)lvlf;

    int sz; size_t lvl_off;
    if      (l == 0) { sz = 200; lvl_off = WS_OFF0; }
    else if (l == 1) { sz = 100; lvl_off = WS_OFF1; }
    else if (l == 2) { sz = 50;  lvl_off = WS_OFF2; }
    else             { sz = 25;  lvl_off = WS_OFF3; }
    const int HW = sz * sz;
    const float scale = 0.25f / (float)(1 << l);

    const float x0s = box.x * scale, y0s = box.y * scale;
    const float x1s = box.z * scale, y1s = box.w * scale;
    const float bin_w = fmaxf(x1s - x0s, 1.0f) / (float)POUT;
    const float bin_h = fmaxf(y1s - y0s, 1.0f) / (float)POUT;

    auto lo_of = [sz](float coord) -> int {
        float cc = fmaxf(coord, 0.0f);
        int lo0 = (int)floorf(cc);
        return (lo0 >= sz - 1) ? sz - 1 : lo0;
    };
    auto hi_of = [sz](float coord) -> int {
        float cc = fmaxf(coord, 0.0f);
        int lo0 = (int)floorf(cc);
        return (lo0 >= sz - 1) ? sz - 1 : lo0 + 1;
    };
    const int ymin = lo_of(y0s + 0.25f * bin_h);
    const int ymax = hi_of(y0s + 6.75f * bin_h);
    const int xmin = lo_of(x0s + 0.25f * bin_w);
    const int xmax = hi_of(x0s + 6.75f * bin_w);
    const int R  = ymax - ymin + 1;
    const int Cl = xmax - xmin + 1;

    for (int i = t; i < R * 8; i += 128)  sWy[i] = 0.0f;
    for (int i = t; i < Cl * 8; i += 128) sWx[i] = 0.0f;
    __syncthreads();

    if (t < 7) {
        #pragma unroll
        for (int iy = 0; iy < 2; ++iy) {
            const float yc = y0s + ((float)t + ((float)iy + 0.5f) * 0.5f) * bin_h;
            const bool  v  = (yc >= -1.0f) && (yc <= (float)sz);
            const float cc = fmaxf(yc, 0.0f);
            const int lo0  = (int)floorf(cc);
            const bool edge = lo0 >= sz - 1;
            const int lo = edge ? sz - 1 : lo0;
            const int hi = edge ? sz - 1 : lo0 + 1;
            const float fr = edge ? 0.0f : cc - (float)lo0;
            const float m  = v ? 1.0f : 0.0f;
            sWy[(lo - ymin) * 8 + t] += (1.0f - fr) * m;
            sWy[(hi - ymin) * 8 + t] += fr * m;
        }
    } else if (t >= 64 && t < 71) {
        const int q = t - 64;
        #pragma unroll
        for (int ix = 0; ix < 2; ++ix) {
            const float xc = x0s + ((float)q + ((float)ix + 0.5f) * 0.5f) * bin_w;
            const bool  v  = (xc >= -1.0f) && (xc <= (float)sz);
            const float cc = fmaxf(xc, 0.0f);
            const int lo0  = (int)floorf(cc);
            const bool edge = lo0 >= sz - 1;
            const int lo = edge ? sz - 1 : lo0;
            const int hi = edge ? sz - 1 : lo0 + 1;
            const float fr = edge ? 0.0f : cc - (float)lo0;
            const float m  = v ? 0.25f : 0.0f;   // fold subsample mean
            sWx[(lo - xmin) * 8 + q] += (1.0f - fr) * m;
            sWx[(hi - xmin) * 8 + q] += fr * m;
        }
    }
    __syncthreads();

    const int c = half * 128 + t;
    const float* fb = ws + lvl_off + (size_t)b * (size_t)HW * NCH + c;
    const size_t rowstride = (size_t)sz * NCH;

    float acc[49];
    #pragma unroll
    for (int i = 0; i < 49; ++i) acc[i] = 0.0f;

    int y = 0;
    for (; y + 2 <= R; y += 2) {
        float wy0[8], wy1[8];
        *(float4*)&wy0[0] = *(const float4*)&sWy[(y + 0) * 8 + 0];
        *(float4*)&wy0[4] = *(const float4*)&sWy[(y + 0) * 8 + 4];
        *(float4*)&wy1[0] = *(const float4*)&sWy[(y + 1) * 8 + 0];
        *(float4*)&wy1[4] = *(const float4*)&sWy[(y + 1) * 8 + 4];

        float cq0[7], cq1[7];
        #pragma unroll
        for (int q = 0; q < 7; ++q) { cq0[q] = 0.0f; cq1[q] = 0.0f; }

        const float* p0 = fb + ((size_t)(ymin + y) * sz + xmin) * NCH;
        const float* p1 = p0 + rowstride;

        int x = 0;
        for (; x + 4 <= Cl; x += 4) {
            // 8 independent loads (4 share a base w/ imm offsets, x2 rows)
            const float a0 = p0[(x + 0) * NCH], a1 = p0[(x + 1) * NCH];
            const float a2 = p0[(x + 2) * NCH], a3 = p0[(x + 3) * NCH];
            const float b0 = p1[(x + 0) * NCH], b1 = p1[(x + 1) * NCH];
            const float b2 = p1[(x + 2) * NCH], b3 = p1[(x + 3) * NCH];
            #pragma unroll
            for (int k = 0; k < 4; ++k) {
                float wx[8];
                *(float4*)&wx[0] = *(const float4*)&sWx[(x + k) * 8 + 0];
                *(float4*)&wx[4] = *(const float4*)&sWx[(x + k) * 8 + 4];
                const float av = (k == 0) ? a0 : (k == 1) ? a1 : (k == 2) ? a2 : a3;
                const float bv = (k == 0) ? b0 : (k == 1) ? b1 : (k == 2) ? b2 : b3;
                #pragma unroll
                for (int q = 0; q < 7; ++q) {
                    cq0[q] += av * wx[q];
                    cq1[q] += bv * wx[q];
                }
            }
        }
        for (; x < Cl; ++x) {
            const float av = p0[x * NCH];
            const float bv = p1[x * NCH];
            float wx[8];
            *(float4*)&wx[0] = *(const float4*)&sWx[x * 8 + 0];
            *(float4*)&wx[4] = *(const float4*)&sWx[x * 8 + 4];
            #pragma unroll
            for (int q = 0; q < 7; ++q) {
                cq0[q] += av * wx[q];
                cq1[q] += bv * wx[q];
            }
        }

        #pragma unroll
        for (int p = 0; p < 7; ++p)
            #pragma unroll
            for (int q = 0; q < 7; ++q)
                acc[p * 7 + q] += wy0[p] * cq0[q] + wy1[p] * cq1[q];
    }
    if (y < R) {
        float wy0[8];
        *(float4*)&wy0[0] = *(const float4*)&sWy[y * 8 + 0];
        *(float4*)&wy0[4] = *(const float4*)&sWy[y * 8 + 4];
        float cq0[7];
        #pragma unroll
        for (int q = 0; q < 7; ++q) cq0[q] = 0.0f;
        const float* p0 = fb + ((size_t)(ymin + y) * sz + xmin) * NCH;
        int x = 0;
        for (; x + 4 <= Cl; x += 4) {
            const float a0 = p0[(x + 0) * NCH], a1 = p0[(x + 1) * NCH];
            const float a2 = p0[(x + 2) * NCH], a3 = p0[(x + 3) * NCH];
            #pragma unroll
            for (int k = 0; k < 4; ++k) {
                float wx[8];
                *(float4*)&wx[0] = *(const float4*)&sWx[(x + k) * 8 + 0];
                *(float4*)&wx[4] = *(const float4*)&sWx[(x + k) * 8 + 4];
                const float av = (k == 0) ? a0 : (k == 1) ? a1 : (k == 2) ? a2 : a3;
                #pragma unroll
                for (int q = 0; q < 7; ++q) cq0[q] += av * wx[q];
            }
        }
        for (; x < Cl; ++x) {
            const float av = p0[x * NCH];
            float wx[8];
            *(float4*)&wx[0] = *(const float4*)&sWx[x * 8 + 0];
            *(float4*)&wx[4] = *(const float4*)&sWx[x * 8 + 4];
            #pragma unroll
            for (int q = 0; q < 7; ++q) cq0[q] += av * wx[q];
        }
        #pragma unroll
        for (int p = 0; p < 7; ++p)
            #pragma unroll
            for (int q = 0; q < 7; ++q)
                acc[p * 7 + q] += wy0[p] * cq0[q];
    }

    // ---- staged coalesced stores (smem reused as 64x49 stage) ----
    __syncthreads();                   // weights dead; smem becomes stage
    const int wave = t >> 6, lane = t & 63;
    float* stage = smem;               // 3136 floats
    // this block's output chunk: channels [half*128, half*128+128)
    float* obase = out + (size_t)n * (NCH * 49) + (size_t)half * 128 * 49;
    #pragma unroll
    for (int w = 0; w < 2; ++w) {
        if (wave == w) {
            #pragma unroll
            for (int i = 0; i < 49; ++i) stage[lane * 49 + i] = acc[i];
        }
        __syncthreads();
        float4* dst4 = (float4*)(obase + w * (64 * 49));
        const float4* src4 = (const float4*)stage;
        for (int i = t; i < 64 * 49 / 4; i += 128) dst4[i] = src4[i];
        __syncthreads();
    }
}

// ---------------- fallback (round-1 NCHW kernel) ----------------
__global__ __launch_bounds__(256, 4) void roi_align_nchw_kernel(
    const float* __restrict__ f0, const float* __restrict__ f1,
    const float* __restrict__ f2, const float* __restrict__ f3,
    const float* __restrict__ props, float* __restrict__ out, int boxes_per_img)
{
    const int n = blockIdx.x;
    const int t = threadIdx.x;
    if (t >= 196) return;
    const int bin = t >> 2, q = t & 3;
    const int ph = bin / POUT, pw = bin % POUT;
    const int iy = q >> 1,    ix = q & 1;
    const int b = n / boxes_per_img;

    const float4 box = ((const float4*)props)[n];
    const float area = (box.z - box.x) * (box.w - box.y);
    float lvlf = floorf(4.0f + log2f(sqrtf(area) / 224.0f + 1e-6f));
    lvlf = fminf(fmaxf(lvlf, 2.0f), 5.0f) - 2.0f;
    const int l = (int)lvlf;

    const float* feat; int sz;
    if      (l == 0) { feat = f0; sz = 200; }
    else if (l == 1) { feat = f1; sz = 100; }
    else if (l == 2) { feat = f2; sz = 50;  }
    else             { feat = f3; sz = 25;  }
    const float scale = 0.25f / (float)(1 << l);

    const float x0 = box.x * scale, y0 = box.y * scale;
    const float x1 = box.z * scale, y1 = box.w * scale;
    const float bin_w = fmaxf(x1 - x0, 1.0f) / (float)POUT;
    const float bin_h = fmaxf(y1 - y0, 1.0f) / (float)POUT;
    const float ysamp = y0 + ((float)ph + ((float)iy + 0.5f) * 0.5f) * bin_h;
    const float xsamp = x0 + ((float)pw + ((float)ix + 0.5f) * 0.5f) * bin_w;

    const bool  vy  = (ysamp >= -1.0f) && (ysamp <= (float)sz);
    const float cy  = fmaxf(ysamp, 0.0f);
    const int   yl0 = (int)floorf(cy);
    const bool  ey  = yl0 >= sz - 1;
    const int   yl  = ey ? sz - 1 : yl0;
    const int   yh  = ey ? sz - 1 : yl0 + 1;
    const float ly  = ey ? 0.0f : cy - (float)yl0;
    const bool  vx  = (xsamp >= -1.0f) && (xsamp <= (float)sz);
    const float cx  = fmaxf(xsamp, 0.0f);
    const int   xl0 = (int)floorf(cx);
    const bool  ex  = xl0 >= sz - 1;
    const int   xl  = ex ? sz - 1 : xl0;
    const int   xh  = ex ? sz - 1 : xl0 + 1;
    const float lx  = ex ? 0.0f : cx - (float)xl0;

    const float hy = 1.0f - ly, hx = 1.0f - lx;
    const float m  = (vy && vx) ? 1.0f : 0.0f;
    const float w00 = hy * hx * m, w01 = hy * lx * m;
    const float w10 = ly * hx * m, w11 = ly * lx * m;

    const int HW = sz * sz;
    const float* base = feat + (size_t)b * NCH * HW;
    int o00 = yl * sz + xl, o01 = yl * sz + xh;
    int o10 = yh * sz + xl, o11 = yh * sz + xh;
    float* op = out + (size_t)n * NCH * (POUT * POUT) + bin;

    #pragma unroll 4
    for (int cch = 0; cch < NCH; ++cch) {
        float v = w00 * base[o00] + w01 * base[o01]
                + w10 * base[o10] + w11 * base[o11];
        v += __shfl_xor(v, 1);
        v += __shfl_xor(v, 2);
        if (q == 0) op[cch * (POUT * POUT)] = v * 0.25f;
        o00 += HW; o01 += HW; o10 += HW; o11 += HW;
    }
}

extern "C" void kernel_launch(void* const* d_in, const int* in_sizes, int n_in,
                              void* d_out, int out_size, void* d_ws, size_t ws_size,
                              hipStream_t stream) {
    const float* f0 = (const float*)d_in[0];
    const float* f1 = (const float*)d_in[1];
    const float* f2 = (const float*)d_in[2];
    const float* f3 = (const float*)d_in[3];
    const float* props = (const float*)d_in[4];
    float* out = (float*)d_out;

    const int N = in_sizes[4] / 4;                 // 1024 boxes
    const int B = in_sizes[0] / (NCH * HW0);       // 2 images
    const int boxes_per_img = N / B;               // 512

    if (ws_size >= (size_t)WS_ELEMS * sizeof(float)) {
        float* wsf = (float*)d_ws;
        dim3 blk(32, 8, 1);
        transpose_cl_kernel<<<dim3((HW0 + 31) / 32, 8, B), blk, 0, stream>>>(f0, wsf + WS_OFF0, HW0);
        transpose_cl_kernel<<<dim3((HW1 + 31) / 32, 8, B), blk, 0, stream>>>(f1, wsf + WS_OFF1, HW1);
        transpose_cl_kernel<<<dim3((HW2 + 31) / 32, 8, B), blk, 0, stream>>>(f2, wsf + WS_OFF2, HW2);
        transpose_cl_kernel<<<dim3((HW3 + 31) / 32, 8, B), blk, 0, stream>>>(f3, wsf + WS_OFF3, HW3);
        roi_sep2_kernel<<<N * 2, 128, 0, stream>>>(wsf, props, out, boxes_per_img);
    } else {
        roi_align_nchw_kernel<<<N, 256, 0, stream>>>(f0, f1, f2, f3, props, out, boxes_per_img);
    }
}